// Round 4
// baseline (240.687 us; speedup 1.0000x reference)
//
#include <hip/hip_runtime.h>
#include <hip/hip_bf16.h>

// Problem constants (fixed by the reference)
#define NROWS 262144
#define KVOL  27
#define CIN   32
#define COUT  64
#define BN_EPS 1e-5f

using bf16x8 = __attribute__((ext_vector_type(8))) short;  // 8 bf16 = 4 VGPRs (MFMA A/B frag)
using f32x4  = __attribute__((ext_vector_type(4))) float;  // MFMA C/D frag

// ---- workspace layout (bytes) ----
#define OFF_XB  0ull                                      // x bf16: 16 MiB
#define OFF_WF  (16ull<<20)                               // W frags: 110592 B
#define OFF_ACC ((16ull<<20) + (128ull<<10))              // sum[64], sumsq[64]
#define OFF_Y   (17ull<<20)                               // y bf16: 32 MiB

__device__ __forceinline__ unsigned short f2bf(float f) {
    __hip_bfloat16 h = __float2bfloat16(f);
    return __builtin_bit_cast(unsigned short, h);
}

// ---- kernel 0: merged {x f32->bf16} + {W repack} + {zero accumulators} ----
__global__ void k_prep(const float4* __restrict__ x4, ushort4* __restrict__ xb4,
                       const float* __restrict__ W, __hip_bfloat16* __restrict__ wf,
                       float* __restrict__ gacc) {
    int bid = blockIdx.x, tid = threadIdx.x;
    if (bid < 8192) {
        int i = bid * 256 + tid;
        float4 v = x4[i];
        ushort4 o;
        o.x = f2bf(v.x); o.y = f2bf(v.y); o.z = f2bf(v.z); o.w = f2bf(v.w);
        xb4[i] = o;
    } else {
        int kk = bid - 8192;            // 0..26
        int t = tid >> 6, l = tid & 63;
        int c0 = (l >> 4) * 8;
        int co = t * 16 + (l & 15);
        // Wfrag[kk][t][lane][j] = W[kk][(lane>>4)*8+j][t*16+(lane&15)]
        __hip_bfloat16* dst = wf + ((size_t)(kk * 4 + t) * 64 + l) * 8;
        #pragma unroll
        for (int j = 0; j < 8; ++j)
            dst[j] = __float2bfloat16(W[(size_t)(kk * CIN + c0 + j) * COUT + co]);
        if (kk == 0 && tid < 128) gacc[tid] = 0.0f;   // ws is poisoned 0xAA
    }
}

// ---- kernel 1: gather + MFMA GEMM -> y(bf16), per-channel sum/sumsq ----
// Block = 256 thr = 4 waves; block owns 128 rows; wave owns 32 rows x 64 cols.
// Software pipeline: a-gathers at depth-3 (4-buffer rotation), b-loads at
// depth-1 (double buffer). Issue order per phase [LOADB(kk+1), GATHER(kk+3),
// MFMA(kk)] makes the compiler's counted vmcnt wait keep {a(kk+2), b(kk+1),
// a(kk+3)} = 4 gather instrs (64 cache lines) in flight per wave, vs ~2 in R2
// where b was loaded at depth-0 and its wait drained the gather FIFO.
__global__ void __launch_bounds__(256, 4)
k_gemm(const __hip_bfloat16* __restrict__ xb, const __hip_bfloat16* __restrict__ wf,
       const int* __restrict__ idx, __hip_bfloat16* __restrict__ y,
       float* __restrict__ gacc) {
    __shared__ int s_idx[128 * KVOL];       // 13824 B
    __shared__ float ssum[4][64];
    __shared__ float ssq[4][64];

    const int tid  = threadIdx.x;
    const int w    = tid >> 6;
    const int l    = tid & 63;
    const int lrow = l & 15;      // A row / D col within frag
    const int lk8  = l >> 4;      // k-group (A/B) and row-group (D)
    const int wrb  = w * 32;                       // wave row base within block
    const int rb   = blockIdx.x * 128 + wrb;       // global row base

    // stage this block's idx rows: 128*27 ints, coalesced
    {
        const int* src = idx + (size_t)blockIdx.x * 128 * KVOL;
        for (int i = tid; i < 128 * KVOL; i += 256) s_idx[i] = src[i];
    }
    __syncthreads();

    f32x4 acc[2][4] = {};
    const bf16x8* wf8 = (const bf16x8*)wf;
    const int koff = lk8 * 8;              // lane's 16B chunk within a 64B row
    const int r0 = (wrb + lrow) * KVOL;    // s_idx row bases for the two m-frags
    const int r1 = (wrb + 16 + lrow) * KVOL;

    bf16x8 abuf[4][2];   // [phase mod 4][m]  -- depth-3 gather rotation
    bf16x8 bbuf[2][4];   // [phase mod 2][t]  -- depth-1 W-frag double buffer

    // prologue: gathers for kk=0,1,2 ; b for kk=0
    #pragma unroll
    for (int kk = 0; kk < 3; ++kk) {
        int i0 = s_idx[r0 + kk], i1 = s_idx[r1 + kk];
        abuf[kk][0] = *(const bf16x8*)(xb + (size_t)((unsigned)i0 * CIN) + koff);
        abuf[kk][1] = *(const bf16x8*)(xb + (size_t)((unsigned)i1 * CIN) + koff);
    }
    #pragma unroll
    for (int t = 0; t < 4; ++t) bbuf[0][t] = wf8[t * 64 + l];

    #pragma unroll
    for (int kk = 0; kk < KVOL; ++kk) {
        if (kk + 1 < KVOL) {   // b(kk+1), depth-1
            #pragma unroll
            for (int t = 0; t < 4; ++t)
                bbuf[(kk + 1) & 1][t] = wf8[((kk + 1) * 4 + t) * 64 + l];
        }
        if (kk + 3 < KVOL) {   // a(kk+3), depth-3, into the buffer freed at kk-1
            int i0 = s_idx[r0 + kk + 3], i1 = s_idx[r1 + kk + 3];
            abuf[(kk + 3) & 3][0] = *(const bf16x8*)(xb + (size_t)((unsigned)i0 * CIN) + koff);
            abuf[(kk + 3) & 3][1] = *(const bf16x8*)(xb + (size_t)((unsigned)i1 * CIN) + koff);
        }
        #pragma unroll
        for (int m = 0; m < 2; ++m)
            #pragma unroll
            for (int t = 0; t < 4; ++t)
                acc[m][t] = __builtin_amdgcn_mfma_f32_16x16x32_bf16(abuf[kk & 3][m], bbuf[kk & 1][t], acc[m][t], 0, 0, 0);
    }

    // epilogue: store y (bf16) + per-channel sums
    float s[4] = {0, 0, 0, 0}, sq[4] = {0, 0, 0, 0};
    #pragma unroll
    for (int m = 0; m < 2; ++m) {
        #pragma unroll
        for (int r = 0; r < 4; ++r) {
            int row = rb + m * 16 + lk8 * 4 + r;   // D: row=(l>>4)*4+reg, col=l&15
            #pragma unroll
            for (int t = 0; t < 4; ++t) {
                float v = acc[m][t][r];
                y[(size_t)row * COUT + t * 16 + lrow] = __float2bfloat16(v);
                s[t] += v;
                sq[t] += v * v;
            }
        }
    }
    #pragma unroll
    for (int t = 0; t < 4; ++t) {
        s[t]  += __shfl_xor(s[t], 16, 64);  s[t]  += __shfl_xor(s[t], 32, 64);
        sq[t] += __shfl_xor(sq[t], 16, 64); sq[t] += __shfl_xor(sq[t], 32, 64);
    }
    if (l < 16) {
        #pragma unroll
        for (int t = 0; t < 4; ++t) { ssum[w][t * 16 + l] = s[t]; ssq[w][t * 16 + l] = sq[t]; }
    }
    __syncthreads();
    if (tid < 64) {
        float ts = 0, tq = 0;
        #pragma unroll
        for (int ww = 0; ww < 4; ++ww) { ts += ssum[ww][tid]; tq += ssq[ww][tid]; }
        atomicAdd(&gacc[tid], ts);
        atomicAdd(&gacc[64 + tid], tq);
    }
}

// ---- kernel 2: stats (redundant per block, trivial) + out = relu(y*sc+sh) ----
__global__ void k_apply(const uint4* __restrict__ y8, const float* __restrict__ gacc,
                        const float* __restrict__ gamma, const float* __restrict__ beta,
                        float* __restrict__ out) {
    __shared__ float s_sc[64], s_sh[64];
    const int tid = threadIdx.x;
    if (tid < 64) {
        float inv_n = 1.0f / (float)NROWS;
        float mean = gacc[tid] * inv_n;
        float var  = gacc[64 + tid] * inv_n - mean * mean;
        float rstd = rsqrtf(var + BN_EPS);
        float sc = gamma[tid] * rstd;
        s_sc[tid] = sc;
        s_sh[tid] = beta[tid] - mean * sc;
    }
    __syncthreads();

    const int nchunk = NROWS * COUT / 8;
    int i0 = blockIdx.x * blockDim.x + tid;
    int c0 = (i0 * 8) & 63;   // thread stride * 8 is a multiple of 64 -> fixed cols
    float sc[8], sh[8];
    #pragma unroll
    for (int j = 0; j < 8; ++j) { sc[j] = s_sc[c0 + j]; sh[j] = s_sh[c0 + j]; }
    for (int i = i0; i < nchunk; i += gridDim.x * blockDim.x) {
        uint4 v = y8[i];
        const unsigned short* p = (const unsigned short*)&v;
        float r[8];
        #pragma unroll
        for (int j = 0; j < 8; ++j) {
            float f = __uint_as_float((unsigned)p[j] << 16);
            r[j] = fmaxf(0.0f, f * sc[j] + sh[j]);
        }
        float4* o = (float4*)(out + (size_t)i * 8);
        o[0] = make_float4(r[0], r[1], r[2], r[3]);
        o[1] = make_float4(r[4], r[5], r[6], r[7]);
    }
}

extern "C" void kernel_launch(void* const* d_in, const int* in_sizes, int n_in,
                              void* d_out, int out_size, void* d_ws, size_t ws_size,
                              hipStream_t stream) {
    const float* x     = (const float*)d_in[0];
    const float* W     = (const float*)d_in[1];
    // d_in[2] = b : cancels under batch-norm, unused
    const float* gamma = (const float*)d_in[3];
    const float* beta  = (const float*)d_in[4];
    const int*   idx   = (const int*)d_in[5];

    char* ws = (char*)d_ws;
    __hip_bfloat16* xb   = (__hip_bfloat16*)(ws + OFF_XB);
    __hip_bfloat16* wf   = (__hip_bfloat16*)(ws + OFF_WF);
    float*          gacc = (float*)(ws + OFF_ACC);
    __hip_bfloat16* y    = (__hip_bfloat16*)(ws + OFF_Y);
    float*          out  = (float*)d_out;

    k_prep<<<8192 + KVOL, 256, 0, stream>>>((const float4*)x, (ushort4*)xb, W, wf, gacc);
    k_gemm<<<NROWS / 128, 256, 0, stream>>>(xb, wf, idx, y, gacc);
    k_apply<<<2048, 256, 0, stream>>>((const uint4*)y, gacc, gamma, beta, out);
}

// Round 11
// 234.210 us; speedup vs baseline: 1.0277x; 1.0277x over previous
//
#include <hip/hip_runtime.h>
#include <hip/hip_bf16.h>

// Problem constants (fixed by the reference)
#define NROWS 262144
#define KVOL  27
#define CIN   32
#define COUT  64
#define BN_EPS 1e-5f

using bf16x8 = __attribute__((ext_vector_type(8))) short;  // 8 bf16 = 4 VGPRs (MFMA A/B frag)
using f32x4  = __attribute__((ext_vector_type(4))) float;  // MFMA C/D frag

// ---- workspace layout (bytes) ----
#define OFF_XB  0ull                                      // x bf16: 16 MiB
#define OFF_WF  (16ull<<20)                               // W frags: 110592 B
#define OFF_ACC ((16ull<<20) + (128ull<<10))              // sum[64], sumsq[64]
#define OFF_Y   (17ull<<20)                               // y bf16: 32 MiB

__device__ __forceinline__ unsigned short f2bf(float f) {
    __hip_bfloat16 h = __float2bfloat16(f);
    return __builtin_bit_cast(unsigned short, h);
}

// ---- kernel 0: merged {x f32->bf16} + {W repack} + {zero accumulators} ----
__global__ void k_prep(const float4* __restrict__ x4, ushort4* __restrict__ xb4,
                       const float* __restrict__ W, __hip_bfloat16* __restrict__ wf,
                       float* __restrict__ gacc) {
    int bid = blockIdx.x, tid = threadIdx.x;
    if (bid < 8192) {
        int i = bid * 256 + tid;
        float4 v = x4[i];
        ushort4 o;
        o.x = f2bf(v.x); o.y = f2bf(v.y); o.z = f2bf(v.z); o.w = f2bf(v.w);
        xb4[i] = o;
    } else {
        int kk = bid - 8192;            // 0..26
        int t = tid >> 6, l = tid & 63;
        int c0 = (l >> 4) * 8;
        int co = t * 16 + (l & 15);
        // Wfrag[kk][t][lane][j] = W[kk][(lane>>4)*8+j][t*16+(lane&15)]
        __hip_bfloat16* dst = wf + ((size_t)(kk * 4 + t) * 64 + l) * 8;
        #pragma unroll
        for (int j = 0; j < 8; ++j)
            dst[j] = __float2bfloat16(W[(size_t)(kk * CIN + c0 + j) * COUT + co]);
        if (kk == 0 && tid < 128) gacc[tid] = 0.0f;   // ws is poisoned 0xAA
    }
}

// ---- kernel 1: gather + MFMA GEMM -> y(bf16), per-channel sum/sumsq ----
// Block = 256 thr = 4 waves; block owns 128 rows; wave owns 32 rows x 64 cols.
// Pipeline ENFORCED with sched_barrier(0) fences (R4's version compiled to
// VGPR=52: the scheduler sank all loads next to their MFMAs, depth collapsed
// to ~1). Per phase kk: {idx(kk+4)->regs, b(kk+1), gather(kk+3)} | fence |
// MFMA(kk) | fence. Pinned order makes the auto-waitcnt at MFMA(kk) a counted
// vmcnt(8): a(kk+2),b(kk+1),a(kk+3) stay in flight across the MFMA cluster.
__global__ void __launch_bounds__(256, 4)
k_gemm(const __hip_bfloat16* __restrict__ xb, const __hip_bfloat16* __restrict__ wf,
       const int* __restrict__ idx, __hip_bfloat16* __restrict__ y,
       float* __restrict__ gacc) {
    __shared__ int s_idx[128 * KVOL];       // 13824 B
    __shared__ float ssum[4][64];
    __shared__ float ssq[4][64];

    const int tid  = threadIdx.x;
    const int w    = tid >> 6;
    const int l    = tid & 63;
    const int lrow = l & 15;      // A row / D col within frag
    const int lk8  = l >> 4;      // k-group (A/B) and row-group (D)
    const int wrb  = w * 32;                       // wave row base within block
    const int rb   = blockIdx.x * 128 + wrb;       // global row base

    // stage this block's idx rows: 128*27 ints, coalesced
    {
        const int* src = idx + (size_t)blockIdx.x * 128 * KVOL;
        for (int i = tid; i < 128 * KVOL; i += 256) s_idx[i] = src[i];
    }
    __syncthreads();

    f32x4 acc[2][4] = {};
    const bf16x8* wf8 = (const bf16x8*)wf;
    const int koff = lk8 * 8;              // lane's 16B chunk within a 64B row
    const int r0 = (wrb + lrow) * KVOL;    // s_idx row bases for the two m-frags
    const int r1 = (wrb + 16 + lrow) * KVOL;

    bf16x8 abuf[4][2];   // [phase mod 4][m]  -- depth-3 gather rotation
    bf16x8 bbuf[2][4];   // [phase mod 2][t]  -- depth-1 W-frag double buffer
    int    idp[2][2];    // [phase mod 2][m]  -- idx prefetch at depth-4

    // prologue: gathers for kk=0,1,2 ; idx(3) prefetch ; b(0)
    #pragma unroll
    for (int kk = 0; kk < 3; ++kk) {
        int i0 = s_idx[r0 + kk], i1 = s_idx[r1 + kk];
        abuf[kk][0] = *(const bf16x8*)(xb + (size_t)((unsigned)i0 * CIN) + koff);
        abuf[kk][1] = *(const bf16x8*)(xb + (size_t)((unsigned)i1 * CIN) + koff);
    }
    idp[1][0] = s_idx[r0 + 3];
    idp[1][1] = s_idx[r1 + 3];
    #pragma unroll
    for (int t = 0; t < 4; ++t) bbuf[0][t] = wf8[t * 64 + l];

    #pragma unroll
    for (int kk = 0; kk < KVOL; ++kk) {
        // --- load-issue region (order pinned vs MFMA below) ---
        if (kk + 4 < KVOL) {   // idx(kk+4) -> regs ((kk+4)&1 == kk&1)
            idp[kk & 1][0] = s_idx[r0 + kk + 4];
            idp[kk & 1][1] = s_idx[r1 + kk + 4];
        }
        if (kk + 1 < KVOL) {   // b(kk+1), depth-1
            #pragma unroll
            for (int t = 0; t < 4; ++t)
                bbuf[(kk + 1) & 1][t] = wf8[((kk + 1) * 4 + t) * 64 + l];
        }
        if (kk + 3 < KVOL) {   // a(kk+3), depth-3, idx prefetched last phase
            int i0 = idp[(kk + 3) & 1][0], i1 = idp[(kk + 3) & 1][1];
            abuf[(kk + 3) & 3][0] = *(const bf16x8*)(xb + (size_t)((unsigned)i0 * CIN) + koff);
            abuf[(kk + 3) & 3][1] = *(const bf16x8*)(xb + (size_t)((unsigned)i1 * CIN) + koff);
        }
        __builtin_amdgcn_sched_barrier(0);   // loads may not sink past here
        #pragma unroll
        for (int m = 0; m < 2; ++m)
            #pragma unroll
            for (int t = 0; t < 4; ++t)
                acc[m][t] = __builtin_amdgcn_mfma_f32_16x16x32_bf16(abuf[kk & 3][m], bbuf[kk & 1][t], acc[m][t], 0, 0, 0);
        __builtin_amdgcn_sched_barrier(0);   // next-phase loads may not hoist in
    }

    // epilogue: store y (bf16) + per-channel sums
    float s[4] = {0, 0, 0, 0}, sq[4] = {0, 0, 0, 0};
    #pragma unroll
    for (int m = 0; m < 2; ++m) {
        #pragma unroll
        for (int r = 0; r < 4; ++r) {
            int row = rb + m * 16 + lk8 * 4 + r;   // D: row=(l>>4)*4+reg, col=l&15
            #pragma unroll
            for (int t = 0; t < 4; ++t) {
                float v = acc[m][t][r];
                y[(size_t)row * COUT + t * 16 + lrow] = __float2bfloat16(v);
                s[t] += v;
                sq[t] += v * v;
            }
        }
    }
    #pragma unroll
    for (int t = 0; t < 4; ++t) {
        s[t]  += __shfl_xor(s[t], 16, 64);  s[t]  += __shfl_xor(s[t], 32, 64);
        sq[t] += __shfl_xor(sq[t], 16, 64); sq[t] += __shfl_xor(sq[t], 32, 64);
    }
    if (l < 16) {
        #pragma unroll
        for (int t = 0; t < 4; ++t) { ssum[w][t * 16 + l] = s[t]; ssq[w][t * 16 + l] = sq[t]; }
    }
    __syncthreads();
    if (tid < 64) {
        float ts = 0, tq = 0;
        #pragma unroll
        for (int ww = 0; ww < 4; ++ww) { ts += ssum[ww][tid]; tq += ssq[ww][tid]; }
        atomicAdd(&gacc[tid], ts);
        atomicAdd(&gacc[64 + tid], tq);
    }
}

// ---- kernel 2: stats (redundant per block, trivial) + out = relu(y*sc+sh) ----
__global__ void k_apply(const uint4* __restrict__ y8, const float* __restrict__ gacc,
                        const float* __restrict__ gamma, const float* __restrict__ beta,
                        float* __restrict__ out) {
    __shared__ float s_sc[64], s_sh[64];
    const int tid = threadIdx.x;
    if (tid < 64) {
        float inv_n = 1.0f / (float)NROWS;
        float mean = gacc[tid] * inv_n;
        float var  = gacc[64 + tid] * inv_n - mean * mean;
        float rstd = rsqrtf(var + BN_EPS);
        float sc = gamma[tid] * rstd;
        s_sc[tid] = sc;
        s_sh[tid] = beta[tid] - mean * sc;
    }
    __syncthreads();

    const int nchunk = NROWS * COUT / 8;
    int i0 = blockIdx.x * blockDim.x + tid;
    int c0 = (i0 * 8) & 63;   // thread stride * 8 is a multiple of 64 -> fixed cols
    float sc[8], sh[8];
    #pragma unroll
    for (int j = 0; j < 8; ++j) { sc[j] = s_sc[c0 + j]; sh[j] = s_sh[c0 + j]; }
    for (int i = i0; i < nchunk; i += gridDim.x * blockDim.x) {
        uint4 v = y8[i];
        const unsigned short* p = (const unsigned short*)&v;
        float r[8];
        #pragma unroll
        for (int j = 0; j < 8; ++j) {
            float f = __uint_as_float((unsigned)p[j] << 16);
            r[j] = fmaxf(0.0f, f * sc[j] + sh[j]);
        }
        float4* o = (float4*)(out + (size_t)i * 8);
        o[0] = make_float4(r[0], r[1], r[2], r[3]);
        o[1] = make_float4(r[4], r[5], r[6], r[7]);
    }
}

extern "C" void kernel_launch(void* const* d_in, const int* in_sizes, int n_in,
                              void* d_out, int out_size, void* d_ws, size_t ws_size,
                              hipStream_t stream) {
    const float* x     = (const float*)d_in[0];
    const float* W     = (const float*)d_in[1];
    // d_in[2] = b : cancels under batch-norm, unused
    const float* gamma = (const float*)d_in[3];
    const float* beta  = (const float*)d_in[4];
    const int*   idx   = (const int*)d_in[5];

    char* ws = (char*)d_ws;
    __hip_bfloat16* xb   = (__hip_bfloat16*)(ws + OFF_XB);
    __hip_bfloat16* wf   = (__hip_bfloat16*)(ws + OFF_WF);
    float*          gacc = (float*)(ws + OFF_ACC);
    __hip_bfloat16* y    = (__hip_bfloat16*)(ws + OFF_Y);
    float*          out  = (float*)d_out;

    k_prep<<<8192 + KVOL, 256, 0, stream>>>((const float4*)x, (ushort4*)xb, W, wf, gacc);
    k_gemm<<<NROWS / 128, 256, 0, stream>>>(xb, wf, idx, y, gacc);
    k_apply<<<2048, 256, 0, stream>>>((const uint4*)y, gacc, gamma, beta, out);
}